// Round 2
// 533.787 us; speedup vs baseline: 1.5193x; 1.5193x over previous
//
#include <hip/hip_runtime.h>
#include <stdint.h>

typedef __bf16 bf16;
typedef __bf16 bf16x8 __attribute__((ext_vector_type(8)));
typedef float f32x4 __attribute__((ext_vector_type(4)));

#define B_DIM 4096
#define HID   1024
#define KPSZ  256

#define BM  128   // m-tile (batch rows)
#define BNH 32    // n-tile within H (x4 gates = 128 weight rows staged)
#define BK  64    // k-step

// ---- runtime dtype detection (unchanged from passing round) --------------
__device__ __forceinline__ bool detect_b16(const void* kps) {
  const uint16_t* k16 = (const uint16_t*)kps;
  int lane = threadIdx.x & 63;
  int c = 0;
#pragma unroll
  for (int j = 0; j < 8; ++j) {
    uint16_t v = k16[(lane * 8 + j) * 2];
    int e = (v >> 7) & 0xFF;
    c += (e >= 100 && e <= 140) ? 1 : 0;
  }
#pragma unroll
  for (int s = 1; s < 64; s <<= 1) c += __shfl_xor(c, s, 64);
  return c > 256;
}

__device__ __forceinline__ bf16x8 load8(const void* base, size_t off, bool b16) {
  if (b16) {
    return *(const bf16x8*)((const bf16*)base + off);
  } else {
    const float* f = (const float*)base + off;
    float4 lo = *(const float4*)f;
    float4 hi = *(const float4*)(f + 4);
    bf16x8 r;
    r[0] = (bf16)lo.x; r[1] = (bf16)lo.y; r[2] = (bf16)lo.z; r[3] = (bf16)lo.w;
    r[4] = (bf16)hi.x; r[5] = (bf16)hi.y; r[6] = (bf16)hi.z; r[7] = (bf16)hi.w;
    return r;
  }
}
__device__ __forceinline__ float ldg1(const void* p, size_t i, bool b16) {
  return b16 ? (float)((const bf16*)p)[i] : ((const float*)p)[i];
}
__device__ __forceinline__ void stg1(void* p, size_t i, float v, bool b16) {
  if (b16) ((bf16*)p)[i] = (bf16)v;
  else     ((float*)p)[i] = v;
}

__device__ __forceinline__ float sigm(float x) {
  return 1.0f / (1.0f + __expf(-x));
}
__device__ __forceinline__ float tanhx(float x) {
  float e = __expf(-2.0f * fabsf(x));
  float t = (1.0f - e) / (1.0f + e);
  return x < 0.0f ? -t : t;
}

// XOR-swizzled LDS index (used by fallback + emb part of prep kernel)
__device__ __forceinline__ int sw(int row, int col8) {
  return row * BK + (col8 ^ ((row & 7) << 3));
}

// async global->LDS, 16B per lane; dest base must be wave-uniform
__device__ __forceinline__ void gl16(const bf16* g, bf16* l) {
  __builtin_amdgcn_global_load_lds(
      (const __attribute__((address_space(1))) void*)g,
      (__attribute__((address_space(3))) void*)l, 16, 0, 0);
}

// ======================= OLD PATH (fallback, verified) =====================

__global__ __launch_bounds__(256)
void emb_kernel(const void* __restrict__ kps, const void* __restrict__ W,
                const void* __restrict__ bias, void* __restrict__ out) {
  __shared__ __align__(16) bf16 sA[BM * BK];   // 16 KB
  __shared__ __align__(16) bf16 sB[BNH * BK];  // 4 KB

  const bool b16 = detect_b16(kps);
  const int n0   = blockIdx.x * BNH;
  const int m0   = blockIdx.y * BM;
  const int tid  = threadIdx.x;
  const int wave = tid >> 6;
  const int lane = tid & 63;
  const int l16  = lane & 15;
  const int kg   = lane >> 4;

  f32x4 acc[2][2] = {};

  bf16x8 ra[4], rb;
  #pragma unroll
  for (int i = 0; i < 4; ++i) {
    int it = tid + i * 256;
    ra[i] = load8(kps, (size_t)(m0 + (it >> 3)) * KPSZ + (it & 7) * 8, b16);
  }
  rb = load8(W, (size_t)(n0 + (tid >> 3)) * KPSZ + (tid & 7) * 8, b16);

  for (int s = 0; s < KPSZ / BK; ++s) {
    __syncthreads();
    #pragma unroll
    for (int i = 0; i < 4; ++i) {
      int it = tid + i * 256;
      *(bf16x8*)(sA + sw(it >> 3, (it & 7) * 8)) = ra[i];
    }
    *(bf16x8*)(sB + sw(tid >> 3, (tid & 7) * 8)) = rb;
    __syncthreads();

    if (s + 1 < KPSZ / BK) {
      int k0 = (s + 1) * BK;
      #pragma unroll
      for (int i = 0; i < 4; ++i) {
        int it = tid + i * 256;
        ra[i] = load8(kps, (size_t)(m0 + (it >> 3)) * KPSZ + k0 + (it & 7) * 8, b16);
      }
      rb = load8(W, (size_t)(n0 + (tid >> 3)) * KPSZ + k0 + (tid & 7) * 8, b16);
    }

    #pragma unroll
    for (int ks = 0; ks < 2; ++ks) {
      bf16x8 a[2], b[2];
      #pragma unroll
      for (int mi = 0; mi < 2; ++mi) {
        int row = wave * 32 + mi * 16 + l16;
        a[mi] = *(const bf16x8*)(sA + sw(row, ks * 32 + kg * 8));
      }
      #pragma unroll
      for (int ni = 0; ni < 2; ++ni) {
        int row = ni * 16 + l16;
        b[ni] = *(const bf16x8*)(sB + sw(row, ks * 32 + kg * 8));
      }
      #pragma unroll
      for (int mi = 0; mi < 2; ++mi)
        #pragma unroll
        for (int ni = 0; ni < 2; ++ni)
          acc[mi][ni] = __builtin_amdgcn_mfma_f32_16x16x32_bf16(a[mi], b[ni], acc[mi][ni], 0, 0, 0);
    }
  }

  #pragma unroll
  for (int mi = 0; mi < 2; ++mi)
    #pragma unroll
    for (int r = 0; r < 4; ++r) {
      int m = m0 + wave * 32 + mi * 16 + kg * 4 + r;
      #pragma unroll
      for (int ni = 0; ni < 2; ++ni) {
        int n = n0 + ni * 16 + l16;
        stg1(out, (size_t)m * KPSZ + n, acc[mi][ni][r] + ldg1(bias, n, b16), b16);
      }
    }
}

struct CellArgs {
  const void *Ax, *Wih, *Ah, *Whh, *bih, *bhh, *Cprev;
  size_t hoff, h2off, coff;
  int Kx, dup;
};
struct Args3 {
  CellArgs c[3];
  void* outbase;
  const void* kps;
};

__global__ __launch_bounds__(256)
void lstm_cells_kernel(Args3 A) {
  __shared__ __align__(16) bf16 sA[BM * BK];        // 16 KB  [128][64] swizzled
  __shared__ __align__(16) bf16 sW[4 * BNH * BK];   // 16 KB  [gate*32 + n32][64] swizzled

  const CellArgs p = A.c[blockIdx.z];
  const bool b16 = detect_b16(A.kps);
  const int n0   = blockIdx.x * BNH;
  const int m0   = blockIdx.y * BM;
  const int tid  = threadIdx.x;
  const int wave = tid >> 6;
  const int lane = tid & 63;
  const int l16  = lane & 15;
  const int kg   = lane >> 4;

  f32x4 acc[4][2][2] = {};

  const int steps1 = p.Kx / BK;
  const int steps  = steps1 + HID / BK;

  bf16x8 ra[4], rw[4];
  #pragma unroll
  for (int i = 0; i < 4; ++i) {
    int it = tid + i * 256;
    ra[i] = load8(p.Ax, (size_t)(m0 + (it >> 3)) * p.Kx + (it & 7) * 8, b16);
  }
  #pragma unroll
  for (int i = 0; i < 4; ++i) {
    int it = tid + i * 256;
    int rr = it >> 3;
    int grow = (rr >> 5) * HID + n0 + (rr & 31);
    rw[i] = load8(p.Wih, (size_t)grow * p.Kx + (it & 7) * 8, b16);
  }

  for (int s = 0; s < steps; ++s) {
    __syncthreads();
    #pragma unroll
    for (int i = 0; i < 4; ++i) {
      int it = tid + i * 256;
      *(bf16x8*)(sA + sw(it >> 3, (it & 7) * 8)) = ra[i];
    }
    #pragma unroll
    for (int i = 0; i < 4; ++i) {
      int it = tid + i * 256;
      *(bf16x8*)(sW + sw(it >> 3, (it & 7) * 8)) = rw[i];
    }
    __syncthreads();

    if (s + 1 < steps) {
      const void *A_, *W_; int K_, k0_;
      int s2 = s + 1;
      if (s2 < steps1) { A_ = p.Ax; W_ = p.Wih; K_ = p.Kx; k0_ = s2 * BK; }
      else             { A_ = p.Ah; W_ = p.Whh; K_ = HID;  k0_ = (s2 - steps1) * BK; }
      #pragma unroll
      for (int i = 0; i < 4; ++i) {
        int it = tid + i * 256;
        ra[i] = load8(A_, (size_t)(m0 + (it >> 3)) * K_ + k0_ + (it & 7) * 8, b16);
      }
      #pragma unroll
      for (int i = 0; i < 4; ++i) {
        int it = tid + i * 256;
        int rr = it >> 3;
        int grow = (rr >> 5) * HID + n0 + (rr & 31);
        rw[i] = load8(W_, (size_t)grow * K_ + k0_ + (it & 7) * 8, b16);
      }
    }

    #pragma unroll
    for (int ks = 0; ks < 2; ++ks) {
      bf16x8 a[2], b[4][2];
      #pragma unroll
      for (int mi = 0; mi < 2; ++mi) {
        int row = wave * 32 + mi * 16 + l16;
        a[mi] = *(const bf16x8*)(sA + sw(row, ks * 32 + kg * 8));
      }
      #pragma unroll
      for (int g = 0; g < 4; ++g)
        #pragma unroll
        for (int ni = 0; ni < 2; ++ni) {
          int row = g * 32 + ni * 16 + l16;
          b[g][ni] = *(const bf16x8*)(sW + sw(row, ks * 32 + kg * 8));
        }
      #pragma unroll
      for (int g = 0; g < 4; ++g)
        #pragma unroll
        for (int mi = 0; mi < 2; ++mi)
          #pragma unroll
          for (int ni = 0; ni < 2; ++ni)
            acc[g][mi][ni] = __builtin_amdgcn_mfma_f32_16x16x32_bf16(
                a[mi], b[g][ni], acc[g][mi][ni], 0, 0, 0);
    }
  }

  float bsum[4][2];
  #pragma unroll
  for (int g = 0; g < 4; ++g)
    #pragma unroll
    for (int ni = 0; ni < 2; ++ni) {
      int n = n0 + ni * 16 + l16;
      bsum[g][ni] = ldg1(p.bih, g * HID + n, b16) + ldg1(p.bhh, g * HID + n, b16);
    }

  #pragma unroll
  for (int mi = 0; mi < 2; ++mi)
    #pragma unroll
    for (int r = 0; r < 4; ++r) {
      int m = m0 + wave * 32 + mi * 16 + kg * 4 + r;
      size_t rowoff = (size_t)m * HID;
      #pragma unroll
      for (int ni = 0; ni < 2; ++ni) {
        int n = n0 + ni * 16 + l16;
        float xi = acc[0][mi][ni][r] + bsum[0][ni];
        float xf = acc[1][mi][ni][r] + bsum[1][ni];
        float xg = acc[2][mi][ni][r] + bsum[2][ni];
        float xo = acc[3][mi][ni][r] + bsum[3][ni];
        float I = sigm(xi);
        float F = sigm(xf);
        float G = tanhx(xg);
        float O = sigm(xo);
        float c  = ldg1(p.Cprev, rowoff + n, b16);
        float cn = F * c + I * G;
        float hn = O * tanhx(cn);
        stg1(A.outbase, p.coff + rowoff + n, cn, b16);
        stg1(A.outbase, p.hoff + rowoff + n, hn, b16);
        if (p.dup) stg1(A.outbase, p.h2off + rowoff + n, hn, b16);
      }
    }
}

// ======================= NEW PATH: bf16 ws + global_load_lds ===============
// prep_kernel: blocks [0,256) = emb GEMM (in_frame bf16 = kps@W_emb^T+b);
//              blocks [256,..) = grid-stride fp32->bf16 convert of 9 tensors.

#define NSEG 9

struct PrepArgs {
  const void* src[NSEG];
  bf16*       dst[NSEG];
  unsigned    pre[NSEG + 1];  // prefix sums of 8-elem chunks
  const void* kps;
  const void* W_emb;
  const void* b_emb;
  bf16*       in_frame;
  int         nconv;          // convert block count
};

__global__ __launch_bounds__(256)
void prep_kernel(PrepArgs P) {
  const bool b16 = detect_b16(P.kps);
  const int tid = threadIdx.x;
  const int bid = blockIdx.x;

  if (bid < 256) {
    // ---------------- emb GEMM (same structure as verified emb_kernel) ----
    __shared__ __align__(16) bf16 sA[BM * BK];
    __shared__ __align__(16) bf16 sB[BNH * BK];
    const int n0   = (bid & 7) * BNH;
    const int m0   = (bid >> 3) * BM;
    const int wave = tid >> 6;
    const int lane = tid & 63;
    const int l16  = lane & 15;
    const int kg   = lane >> 4;

    f32x4 acc[2][2] = {};
    bf16x8 ra[4], rb;
    #pragma unroll
    for (int i = 0; i < 4; ++i) {
      int it = tid + i * 256;
      ra[i] = load8(P.kps, (size_t)(m0 + (it >> 3)) * KPSZ + (it & 7) * 8, b16);
    }
    rb = load8(P.W_emb, (size_t)(n0 + (tid >> 3)) * KPSZ + (tid & 7) * 8, b16);

    for (int s = 0; s < KPSZ / BK; ++s) {
      __syncthreads();
      #pragma unroll
      for (int i = 0; i < 4; ++i) {
        int it = tid + i * 256;
        *(bf16x8*)(sA + sw(it >> 3, (it & 7) * 8)) = ra[i];
      }
      *(bf16x8*)(sB + sw(tid >> 3, (tid & 7) * 8)) = rb;
      __syncthreads();

      if (s + 1 < KPSZ / BK) {
        int k0 = (s + 1) * BK;
        #pragma unroll
        for (int i = 0; i < 4; ++i) {
          int it = tid + i * 256;
          ra[i] = load8(P.kps, (size_t)(m0 + (it >> 3)) * KPSZ + k0 + (it & 7) * 8, b16);
        }
        rb = load8(P.W_emb, (size_t)(n0 + (tid >> 3)) * KPSZ + k0 + (tid & 7) * 8, b16);
      }

      #pragma unroll
      for (int ks = 0; ks < 2; ++ks) {
        bf16x8 a[2], bfr[2];
        #pragma unroll
        for (int mi = 0; mi < 2; ++mi) {
          int row = wave * 32 + mi * 16 + l16;
          a[mi] = *(const bf16x8*)(sA + sw(row, ks * 32 + kg * 8));
        }
        #pragma unroll
        for (int ni = 0; ni < 2; ++ni) {
          int row = ni * 16 + l16;
          bfr[ni] = *(const bf16x8*)(sB + sw(row, ks * 32 + kg * 8));
        }
        #pragma unroll
        for (int mi = 0; mi < 2; ++mi)
          #pragma unroll
          for (int ni = 0; ni < 2; ++ni)
            acc[mi][ni] = __builtin_amdgcn_mfma_f32_16x16x32_bf16(a[mi], bfr[ni], acc[mi][ni], 0, 0, 0);
      }
    }

    #pragma unroll
    for (int mi = 0; mi < 2; ++mi)
      #pragma unroll
      for (int r = 0; r < 4; ++r) {
        int m = m0 + wave * 32 + mi * 16 + kg * 4 + r;
        #pragma unroll
        for (int ni = 0; ni < 2; ++ni) {
          int n = n0 + ni * 16 + l16;
          P.in_frame[(size_t)m * KPSZ + n] = (bf16)(acc[mi][ni][r] + ldg1(P.b_emb, n, b16));
        }
      }
    return;
  }

  // ---------------- convert: grid-stride over concatenated 8-el chunks ----
  const int cb = bid - 256;
  const unsigned tot = P.pre[NSEG];
  const unsigned stride = (unsigned)P.nconv * 256u;
  for (unsigned c = (unsigned)cb * 256u + (unsigned)tid; c < tot; c += stride) {
    int s = 0;
    #pragma unroll
    for (int k = 0; k < NSEG - 1; ++k) s += (c >= P.pre[k + 1]) ? 1 : 0;
    unsigned lc = c - P.pre[s];
    bf16x8 v = load8(P.src[s], (size_t)lc * 8, b16);
    *(bf16x8*)(P.dst[s] + (size_t)lc * 8) = v;
  }
}

// fused 4-gate GEMM + LSTM epilogue, m97-style staging.
// Block: 128 m-rows x (4 gates x 32 n-cols). 4 waves in 2x2:
//   wave (wm,wn): rows wm*64 + mi*16 (mi 0..3), cols n0 + wn*16 (+l16),
//   acc[gate][mi] -> per ks: 4 a-frags + 4 b-frags feed 16 MFMA (m97 reuse).
struct NCell {
  const bf16 *Ax, *Wih, *Ah, *Whh;  // bf16 (workspace)
  const void *bih, *bhh, *Cprev;    // original dtype
  size_t hoff, h2off, coff;
  int Kx, dup;
};
struct NArgs {
  NCell c[3];
  void* outbase;
  const void* kps;
};

__global__ __launch_bounds__(256)
void lstm_fast_kernel(NArgs A) {
  __shared__ __align__(16) bf16 sA[BM * BK];        // 16 KB, linear [128][64]
  __shared__ __align__(16) bf16 sW[4 * BNH * BK];   // 16 KB, linear [128][64]

  const NCell p = A.c[blockIdx.z];
  const bool b16 = detect_b16(A.kps);
  const int n0   = blockIdx.x * BNH;
  const int m0   = blockIdx.y * BM;
  const int tid  = threadIdx.x;
  const int w    = tid >> 6;
  const int lane = tid & 63;
  const int l16  = lane & 15;
  const int kg   = lane >> 4;
  const int wm   = w >> 1;
  const int wn   = w & 1;

  f32x4 acc[4][4] = {};   // [gate][mi]

  const int steps1 = p.Kx / BK;
  const int steps  = steps1 + HID / BK;

  for (int s = 0; s < steps; ++s) {
    const bf16 *A_, *W_; int K_, k0_;
    if (s < steps1) { A_ = p.Ax; W_ = p.Wih; K_ = p.Kx; k0_ = s * BK; }
    else            { A_ = p.Ah; W_ = p.Whh; K_ = HID;  k0_ = (s - steps1) * BK; }

    // stage A tile: 1024 16B-chunks; wave w, call j covers chunks (j*4+w)*64+lane
    #pragma unroll
    for (int j = 0; j < 4; ++j) {
      int c0 = (j * 4 + w) * 64;
      int c  = c0 + lane;
      gl16(A_ + (size_t)(m0 + (c >> 3)) * K_ + k0_ + (c & 7) * 8, sA + c0 * 8);
    }
    // stage W tile: staged row r -> weight row (r>>5)*HID + n0 + (r&31)
    #pragma unroll
    for (int j = 0; j < 4; ++j) {
      int c0 = (j * 4 + w) * 64;
      int c  = c0 + lane;
      int r  = c >> 3;
      int grow = (r >> 5) * HID + n0 + (r & 31);
      gl16(W_ + (size_t)grow * K_ + k0_ + (c & 7) * 8, sW + c0 * 8);
    }
    __syncthreads();   // compiler drains vmcnt(0) before s_barrier -> tiles ready

    #pragma unroll
    for (int ks = 0; ks < 2; ++ks) {
      bf16x8 a[4], b[4];
      #pragma unroll
      for (int mi = 0; mi < 4; ++mi) {
        int row = wm * 64 + mi * 16 + l16;
        a[mi] = *(const bf16x8*)(sA + row * BK + ks * 32 + kg * 8);
      }
      #pragma unroll
      for (int g = 0; g < 4; ++g) {
        int row = g * 32 + wn * 16 + l16;
        b[g] = *(const bf16x8*)(sW + row * BK + ks * 32 + kg * 8);
      }
      #pragma unroll
      for (int g = 0; g < 4; ++g)
        #pragma unroll
        for (int mi = 0; mi < 4; ++mi)
          acc[g][mi] = __builtin_amdgcn_mfma_f32_16x16x32_bf16(a[mi], b[g], acc[g][mi], 0, 0, 0);
    }
    __syncthreads();   // all reads done before next iteration overwrites
  }

  // ---- epilogue: per-lane LSTM cell update --------------------------------
  const int n = n0 + wn * 16 + l16;
  float bsum[4];
  #pragma unroll
  for (int g = 0; g < 4; ++g)
    bsum[g] = ldg1(p.bih, g * HID + n, b16) + ldg1(p.bhh, g * HID + n, b16);

  #pragma unroll
  for (int mi = 0; mi < 4; ++mi)
    #pragma unroll
    for (int r = 0; r < 4; ++r) {
      int m = m0 + wm * 64 + mi * 16 + kg * 4 + r;
      size_t rowoff = (size_t)m * HID;
      float xi = acc[0][mi][r] + bsum[0];
      float xf = acc[1][mi][r] + bsum[1];
      float xg = acc[2][mi][r] + bsum[2];
      float xo = acc[3][mi][r] + bsum[3];
      float I = sigm(xi);
      float F = sigm(xf);
      float G = tanhx(xg);
      float O = sigm(xo);
      float c  = ldg1(p.Cprev, rowoff + n, b16);
      float cn = F * c + I * G;
      float hn = O * tanhx(cn);
      stg1(A.outbase, p.coff + rowoff + n, cn, b16);
      stg1(A.outbase, p.hoff + rowoff + n, hn, b16);
      if (p.dup) stg1(A.outbase, p.h2off + rowoff + n, hn, b16);
    }
}

extern "C" void kernel_launch(void* const* d_in, const int* in_sizes, int n_in,
                              void* d_out, int out_size, void* d_ws, size_t ws_size,
                              hipStream_t stream) {
  const void* kps   = d_in[0];
  const void* h0    = d_in[1];
  const void* h1    = d_in[2];
  const void* h2    = d_in[3];
  const void* c0    = d_in[4];
  const void* c1    = d_in[5];
  const void* c2    = d_in[6];
  const void* W_emb = d_in[7];
  const void* b_emb = d_in[8];
  const void* w_ih1 = d_in[9];
  const void* w_hh1 = d_in[10];
  const void* b_ih1 = d_in[11];
  const void* b_hh1 = d_in[12];
  const void* w_ih2 = d_in[13];
  const void* w_hh2 = d_in[14];
  const void* b_ih2 = d_in[15];
  const void* b_hh2 = d_in[16];
  const void* w_ih3 = d_in[17];
  const void* w_hh3 = d_in[18];
  const void* b_ih3 = d_in[19];
  const void* b_hh3 = d_in[20];

  const size_t S = (size_t)B_DIM * HID;

  // bf16 workspace layout (element offsets)
  const size_t E_SMALL = (size_t)4 * HID * KPSZ;   // 1,048,576 (w_ih1 / in_frame)
  const size_t E_BIG   = (size_t)4 * HID * HID;    // 4,194,304
  const size_t TOT_ELEMS = 2 * E_SMALL + 8 * E_BIG;  // 35,651,584
  const size_t NEED = TOT_ELEMS * 2;                 // 71,303,168 B

  if (ws_size >= NEED) {
    bf16* wsb      = (bf16*)d_ws;
    bf16* in_frame = wsb;                       // 1M elems
    bf16* W1x      = wsb + E_SMALL;             // w_ih1
    bf16* W1h      = W1x + E_SMALL;             // w_hh1
    bf16* W2x      = W1h + E_BIG;
    bf16* W2h      = W2x + E_BIG;
    bf16* W3x      = W2h + E_BIG;
    bf16* W3h      = W3x + E_BIG;
    bf16* H0       = W3h + E_BIG;
    bf16* H1       = H0 + E_BIG;
    bf16* H2       = H1 + E_BIG;

    PrepArgs P;
    const void* srcs[NSEG] = { w_ih1, w_hh1, w_ih2, w_hh2, w_ih3, w_hh3, h0, h1, h2 };
    bf16*       dsts[NSEG] = { W1x,   W1h,   W2x,   W2h,   W3x,   W3h,  H0, H1, H2 };
    unsigned    cnts[NSEG] = { (unsigned)(E_SMALL / 8), (unsigned)(E_BIG / 8),
                               (unsigned)(E_BIG / 8),   (unsigned)(E_BIG / 8),
                               (unsigned)(E_BIG / 8),   (unsigned)(E_BIG / 8),
                               (unsigned)(E_BIG / 8),   (unsigned)(E_BIG / 8),
                               (unsigned)(E_BIG / 8) };
    unsigned acc = 0;
    for (int i = 0; i < NSEG; ++i) {
      P.src[i] = srcs[i];
      P.dst[i] = dsts[i];
      P.pre[i] = acc;
      acc += cnts[i];
    }
    P.pre[NSEG] = acc;
    P.kps = kps; P.W_emb = W_emb; P.b_emb = b_emb; P.in_frame = in_frame;
    P.nconv = 2048;

    prep_kernel<<<dim3(256 + 2048), 256, 0, stream>>>(P);

    NArgs N;
    N.outbase = d_out;
    N.kps = kps;
    N.c[0] = { in_frame, W1x, H0, W1h, b_ih1, b_hh1, c0, 1 * S, 0, 4 * S, KPSZ, 0 };
    N.c[1] = { H0,       W2x, H1, W2h, b_ih2, b_hh2, c1, 2 * S, 0, 5 * S, HID,  0 };
    N.c[2] = { H1,       W3x, H2, W3h, b_ih3, b_hh3, c2, 0,     3 * S, 6 * S, HID, 1 };

    lstm_fast_kernel<<<dim3(HID / BNH, B_DIM / BM, 3), 256, 0, stream>>>(N);
    return;
  }

  // -------- fallback: previous verified path --------
  void* in_frame = d_ws;   // [4096 x 256] in detected dtype (<= 4 MB)
  emb_kernel<<<dim3(KPSZ / BNH, B_DIM / BM), 256, 0, stream>>>(kps, W_emb, b_emb, in_frame);

  Args3 A;
  A.outbase = d_out;
  A.kps = kps;
  A.c[0] = { in_frame, w_ih1, h0, w_hh1, b_ih1, b_hh1, c0,
             1 * S, 0, 4 * S, KPSZ, 0 };
  A.c[1] = { h0, w_ih2, h1, w_hh2, b_ih2, b_hh2, c1,
             2 * S, 0, 5 * S, HID, 0 };
  A.c[2] = { h1, w_ih3, h2, w_hh3, b_ih3, b_hh3, c2,
             0 * S, 3 * S, 6 * S, HID, 1 };

  lstm_cells_kernel<<<dim3(HID / BNH, B_DIM / BM, 3), 256, 0, stream>>>(A);
}